// Round 15
// baseline (258.782 us; speedup 1.0000x reference)
//
#include <hip/hip_runtime.h>

// GriddingDistance, single-kernel filter-broadcast structure.
// Output: [pred_grid (8*G) | gt_grid (8*G)] fp32, G = 128^3.
//
// One kernel, 1024 blocks x 1024 thr x 128 KiB LDS: block = (slab, 16x16x128
// region). Each block scans its slab's ENTIRE point array (768 KB, L2-resident
// per-XCD via bijective swizzle: each XCD reads exactly 2 slabs) and filters
// points whose trilinear footprint touches its region (~1157 of 65536; early
// x-reject kills 15/16 in ~6 VALU ops). In-region corners accumulate via LDS
// atomics; exclusive contiguous nontemporal float4 writeback (16 chunks of
// 8 KB). No bins workspace, no memset, no second kernel.

#define RES   128
#define GRIDG (RES * RES * RES)
#define NSLAB 16              // 2 clouds * 8 samples
#define NREG  64              // 8x8 xy-regions of 16x16x128 per slab
#define NBIN  (NSLAB * NREG)  // 1024

typedef float floatx4 __attribute__((ext_vector_type(4)));

__device__ __forceinline__ int clampi(int v) {
    return v < 0 ? 0 : (v > RES - 1 ? RES - 1 : v);
}

__global__ __launch_bounds__(1024) void fused_filter_kernel(
    const float* __restrict__ pred, const float* __restrict__ gt,
    float* __restrict__ out, int npts)
{
    __shared__ __align__(16) float vox[16 * 16 * 128];   // 128 KiB

    // bijective XCD swizzle: XCD x owns bins [x*128, (x+1)*128) = 2 slabs
    const int bid = blockIdx.x;
    const int bin = (bid & 7) * 128 + (bid >> 3);
    const int slab = bin >> 6;
    const int reg  = bin & 63;
    const int rx = reg >> 3, ry = reg & 7;
    const int t = threadIdx.x;

    float4* v4 = (float4*)vox;
    for (int i = t; i < 8192; i += 1024) v4[i] = make_float4(0, 0, 0, 0);
    __syncthreads();

    const float* cbase = ((slab < 8) ? pred : gt) + (size_t)(slab & 7) * npts * 3;
    const float4* b4 = (const float4*)cbase;

    const int niter = npts >> 12;          // npts / 4096 points per iter
    for (int c = 0; c < niter; ++c) {
        const int p4 = c * 1024 + t;       // this thread's 4-point group
        const float4 f0 = b4[3 * p4 + 0];
        const float4 f1 = b4[3 * p4 + 1];
        const float4 f2 = b4[3 * p4 + 2];
        const float gx[4] = {f0.x, f0.w, f1.z, f2.y};
        const float gy[4] = {f0.y, f1.x, f1.w, f2.z};
        const float gz[4] = {f0.z, f1.y, f2.x, f2.w};

#pragma unroll
        for (int k = 0; k < 4; ++k) {
            // early x-reject (most lanes exit here)
            const float x = fmaf(gx[k], 128.0f, 64.0f);
            const int ix = (int)floorf(x);
            const int x0 = clampi(ix), x1 = clampi(ix + 1);
            if ((x0 >> 4) > rx || (x1 >> 4) < rx) continue;
            const float y = fmaf(gy[k], 128.0f, 64.0f);
            const int iy = (int)floorf(y);
            const int y0 = clampi(iy), y1 = clampi(iy + 1);
            if ((y0 >> 4) > ry || (y1 >> 4) < ry) continue;

            const float z = fmaf(gz[k], 128.0f, 64.0f);
            const float zf = floorf(z);
            const int iz = (int)zf;
            const int z0 = clampi(iz), z1 = clampi(iz + 1);
            const float dx = x - floorf(x), dy = y - floorf(y), dz = z - zf;
            const float wx0 = 1.0f - dx, wy0 = 1.0f - dy, wz0 = 1.0f - dz;

#pragma unroll
            for (int sx = 0; sx < 2; ++sx) {
                const int cx = sx ? x1 : x0;
                if ((cx >> 4) != rx) continue;
                const float wx = sx ? dx : wx0;
#pragma unroll
                for (int sy = 0; sy < 2; ++sy) {
                    const int cy = sy ? y1 : y0;
                    if ((cy >> 4) != ry) continue;
                    const float wxy = wx * (sy ? dy : wy0);
                    const int base = ((cx & 15) << 11) | ((cy & 15) << 7);
                    atomicAdd(&vox[base + z0], wxy * wz0);
                    atomicAdd(&vox[base + z1], wxy * dz);
                }
            }
        }
    }
    __syncthreads();

    // exclusive contiguous writeback: 16 chunks (one per local x) of 8 KB
    float* gp = out + (size_t)slab * GRIDG
              + ((size_t)rx << 18) + ((size_t)ry << 11);
    const floatx4* lv = (const floatx4*)vox;
    for (int i = t; i < 8192; i += 1024) {
        const int l   = i << 2;        // float index in LDS
        const int lx  = l >> 11;       // local x (0..15)
        const int rem = l & 2047;      // ly*128+lz, contiguous in global
        __builtin_nontemporal_store(lv[i],
            (floatx4*)(gp + ((size_t)lx << 14) + rem));
    }
}

// ---------------- fallback (R1 measured-correct atomic scatter) ----------------

__global__ __launch_bounds__(256) void gridding_scatter_kernel(
    const float* __restrict__ cloud, float* __restrict__ grid, int n)
{
    const int j = blockIdx.x * blockDim.x + threadIdx.x;
    if (j >= n) return;
    const int b = blockIdx.y;
    const size_t pt = (size_t)b * n + j;

    const float x = fmaf(cloud[pt * 3 + 0], 128.0f, 64.0f);
    const float y = fmaf(cloud[pt * 3 + 1], 128.0f, 64.0f);
    const float z = fmaf(cloud[pt * 3 + 2], 128.0f, 64.0f);
    const float xf = floorf(x), yf = floorf(y), zf = floorf(z);
    const float dx = x - xf, dy = y - yf, dz = z - zf;
    const int ix = (int)xf, iy = (int)yf, iz = (int)zf;
    const int x0 = clampi(ix), x1 = clampi(ix + 1);
    const int y0 = clampi(iy), y1 = clampi(iy + 1);
    const int z0 = clampi(iz), z1 = clampi(iz + 1);
    const float wx0 = 1.0f - dx, wy0 = 1.0f - dy, wz0 = 1.0f - dz;

    float* gp = grid + (size_t)b * GRIDG;
    const int bx0 = x0 << 14, bx1 = x1 << 14;
    const int by0 = y0 << 7,  by1 = y1 << 7;
    atomicAdd(gp + (bx0 + by0 + z0), wx0 * wy0 * wz0);
    atomicAdd(gp + (bx0 + by0 + z1), wx0 * wy0 * dz);
    atomicAdd(gp + (bx0 + by1 + z0), wx0 * dy * wz0);
    atomicAdd(gp + (bx0 + by1 + z1), wx0 * dy * dz);
    atomicAdd(gp + (bx1 + by0 + z0), dx * wy0 * wz0);
    atomicAdd(gp + (bx1 + by0 + z1), dx * wy0 * dz);
    atomicAdd(gp + (bx1 + by1 + z0), dx * dy * wz0);
    atomicAdd(gp + (bx1 + by1 + z1), dx * dy * dz);
}

// ---------------- launcher ----------------

extern "C" void kernel_launch(void* const* d_in, const int* in_sizes, int n_in,
                              void* d_out, int out_size, void* d_ws, size_t ws_size,
                              hipStream_t stream) {
    const float* pred = (const float*)d_in[0];
    const float* gt   = (const float*)d_in[1];
    float* out = (float*)d_out;

    const int bsz  = 8;
    const int npts = in_sizes[0] / (bsz * 3);   // 65536

    if ((npts & 4095) == 0) {
        fused_filter_kernel<<<dim3(NBIN), dim3(1024), 0, stream>>>(
            pred, gt, out, npts);
    } else {
        // fallback: global-atomic scatter
        (void)hipMemsetAsync(d_out, 0, (size_t)out_size * sizeof(float), stream);
        dim3 block(256);
        dim3 grid((npts + 255) / 256, bsz);
        float* pred_grid = out;
        float* gt_grid   = out + (size_t)bsz * GRIDG;
        gridding_scatter_kernel<<<grid, block, 0, stream>>>(pred, pred_grid, npts);
        gridding_scatter_kernel<<<grid, block, 0, stream>>>(gt,   gt_grid,   npts);
    }
}